// Round 11
// baseline (2521.231 us; speedup 1.0000x reference)
//
#include <hip/hip_runtime.h>
#include <hip/hip_bf16.h>
#include <stdint.h>

#define BB 32
#define NN 128
#define TT 16
#define FN 16
#define FE 8
#define FG 8
#define FH 16
#define HH 128
#define DEC 64

// ws layout (floats):
// base_node @0        [524288]
// We        @524288   [1024]
// mg        @525312   [4096]
// eg16      @529408   [2097152]
// jl (int)  @2626560  [524288]
// cnt (int) @3150848  [4096]
// zpart     @3154944  [25165824]  ([16+ steps][3 mats][4096 rows][128])
// bufA      @28320768 [1572864]   ([3][4096][128])
// bufB      @29893632 [1572864]
// end 31466496 floats = 125.9 MB (ws = 256 MB)

__global__ __launch_bounds__(HH) void prep1(const float* __restrict__ node,
                                            const float* __restrict__ Wn,
                                            float* __restrict__ base_node) {
    int row = blockIdx.x;
    int h = threadIdx.x;
    float acc = 0.f;
#pragma unroll
    for (int f = 0; f < FN; ++f)
        acc += node[row * FN + f] * Wn[f * HH + h];
    base_node[row * HH + h] = acc;
}

// grid = BB + FE blocks: 0..31 compute mg[b][h]; 32..39 compute We[f][h].
__global__ __launch_bounds__(HH) void prep2(const float* __restrict__ graph,
                                            const float* __restrict__ Wg,
                                            const float* __restrict__ Wmg,
                                            const float* __restrict__ Wee,
                                            const float* __restrict__ Wme,
                                            float* __restrict__ mg,
                                            float* __restrict__ We) {
    int h = threadIdx.x;
    if (blockIdx.x < BB) {
        int b = blockIdx.x;
        __shared__ float gf[HH];
        float acc = 0.f;
#pragma unroll
        for (int f = 0; f < FG; ++f) acc += graph[b * FG + f] * Wg[f * HH + h];
        gf[h] = acc;
        __syncthreads();
        float a2 = 0.f;
#pragma unroll 16
        for (int k = 0; k < HH; ++k) a2 += gf[k] * Wmg[k * HH + h];
        mg[b * HH + h] = a2;
    } else {
        int f = blockIdx.x - BB;
        float acc = 0.f;
#pragma unroll 16
        for (int k = 0; k < HH; ++k) acc += Wee[f * HH + k] * Wme[k * HH + h];
        We[f * HH + h] = acc;
    }
}

__device__ __forceinline__ uint32_t bf16rne(float v) {
    uint32_t b = __float_as_uint(v);
    return (b + 0x7fffu + ((b >> 16) & 1u)) >> 16;
}

// Compact valid senders into bf16-packed rows; pad count to multiple of 8
// with duplicates of the first valid entry (max is idempotent).
__global__ __launch_bounds__(HH) void prep3(const float* __restrict__ edge,
                                            const int* __restrict__ adj,
                                            uint4* __restrict__ eg16,
                                            int* __restrict__ jl,
                                            int* __restrict__ cnt) {
    int bi = blockIdx.x;
    int j = threadIdx.x;
    __shared__ int w0cnt, totc, j0s;
    bool valid = adj[(size_t)bi * NN + j] > 0;
    unsigned long long mask = __ballot(valid);
    int lane = j & 63;
    int wave = j >> 6;
    int prefix = __popcll(mask & ((1ull << lane) - 1ull));
    int wcount = __popcll(mask);
    if (wave == 0 && lane == 0) w0cnt = wcount;
    __syncthreads();
    int base = (wave == 1) ? w0cnt : 0;
    if (wave == 1 && lane == 0) totc = w0cnt + wcount;
    int pos = base + prefix;
    if (valid && pos == 0) j0s = j;
    __syncthreads();
    int c = totc;
    int cpad = (c + 7) & ~7;
    if (j == 0) cnt[bi] = cpad;

    if (valid) {
        jl[bi * NN + pos] = j;
        const float* src = edge + ((size_t)bi * NN + j) * FE;
        uint4 r;
        r.x = bf16rne(src[0]) | (bf16rne(src[1]) << 16);
        r.y = bf16rne(src[2]) | (bf16rne(src[3]) << 16);
        r.z = bf16rne(src[4]) | (bf16rne(src[5]) << 16);
        r.w = bf16rne(src[6]) | (bf16rne(src[7]) << 16);
        eg16[(size_t)bi * NN + pos] = r;
    }
    if (c > 0 && j >= c && j < cpad) {
        int j0 = j0s;
        jl[bi * NN + j] = j0;
        const float* src = edge + ((size_t)bi * NN + j0) * FE;
        uint4 r;
        r.x = bf16rne(src[0]) | (bf16rne(src[1]) << 16);
        r.y = bf16rne(src[2]) | (bf16rne(src[3]) << 16);
        r.z = bf16rne(src[4]) | (bf16rne(src[5]) << 16);
        r.w = bf16rne(src[6]) | (bf16rne(src[7]) << 16);
        eg16[(size_t)bi * NN + j] = r;
    }
}

// K0: nf-part GEMM for ALL 16 steps at once. 8192 blocks x 256 thr.
__global__ __launch_bounds__(256) void k0_nf(
    const float* __restrict__ base_node, const float* __restrict__ hints,
    const float* __restrict__ Wh,
    const float* __restrict__ Wm1, const float* __restrict__ Wm2,
    const float* __restrict__ Wo1, const float* __restrict__ mg,
    float* __restrict__ zpart) {
    __shared__ float zs[8][HH];
    const int lane = threadIdx.x & 127;
    const int half = threadIdx.x >> 7;
    const int bid = blockIdx.x;
    const int t = bid >> 9;
    const int bl = bid & 511;
    const int tile = (bl & 7) * 64 + (bl >> 3);
    const int row0 = tile * 8;

#pragma unroll
    for (int r = 0; r < 4; ++r) {
        int rr = half * 4 + r;
        int row = row0 + rr;
        float nf = base_node[row * HH + lane];
        if (t > 0) {
            const float* hr = hints + ((size_t)(t - 1) * BB * NN + row) * FH;
#pragma unroll
            for (int f = 0; f < FH; ++f) nf = fmaf(hr[f], Wh[f * HH + lane], nf);
        }
        zs[rr][lane] = nf;
    }
    __syncthreads();

    float acc[4][3];
#pragma unroll
    for (int r = 0; r < 4; ++r) { acc[r][0] = 0.f; acc[r][1] = 0.f; acc[r][2] = 0.f; }
    const int h4 = half * 4;

#pragma unroll 4
    for (int kk = 0; kk < 32; ++kk) {
        const int k0 = kk * 4;
        float4 z0 = *(const float4*)&zs[h4 + 0][k0];
        float4 z1 = *(const float4*)&zs[h4 + 1][k0];
        float4 z2 = *(const float4*)&zs[h4 + 2][k0];
        float4 z3 = *(const float4*)&zs[h4 + 3][k0];
#define K0U(COMP, KO)                                                   \
        {                                                               \
            const float w1 = Wm1[(k0 + KO) * HH + lane];                \
            const float w2 = Wm2[(k0 + KO) * HH + lane];                \
            const float w3 = Wo1[(k0 + KO) * HH + lane];                \
            acc[0][0] = fmaf(z0.COMP, w1, acc[0][0]);                   \
            acc[1][0] = fmaf(z1.COMP, w1, acc[1][0]);                   \
            acc[2][0] = fmaf(z2.COMP, w1, acc[2][0]);                   \
            acc[3][0] = fmaf(z3.COMP, w1, acc[3][0]);                   \
            acc[0][1] = fmaf(z0.COMP, w2, acc[0][1]);                   \
            acc[1][1] = fmaf(z1.COMP, w2, acc[1][1]);                   \
            acc[2][1] = fmaf(z2.COMP, w2, acc[2][1]);                   \
            acc[3][1] = fmaf(z3.COMP, w2, acc[3][1]);                   \
            acc[0][2] = fmaf(z0.COMP, w3, acc[0][2]);                   \
            acc[1][2] = fmaf(z1.COMP, w3, acc[1][2]);                   \
            acc[2][2] = fmaf(z2.COMP, w3, acc[2][2]);                   \
            acc[3][2] = fmaf(z3.COMP, w3, acc[3][2]);                   \
        }
        K0U(x, 0) K0U(y, 1) K0U(z, 2) K0U(w, 3)
#undef K0U
    }

    const int b = row0 >> 7;
    const float mgv = mg[b * HH + lane];
#pragma unroll
    for (int r = 0; r < 4; ++r) {
        const int row = row0 + h4 + r;
        const size_t o = ((size_t)t * 3 * 4096) * HH;
        zpart[o + ((size_t)0 * 4096 + row) * HH + lane] = acc[r][0] + mgv;
        zpart[o + ((size_t)1 * 4096 + row) * HH + lane] = acc[r][1];
        zpart[o + ((size_t)2 * 4096 + row) * HH + lane] = acc[r][2];
    }
}

// K12: fused per-round kernel. 512 blocks x 1024 thr. Block = 8 receivers of
// one batch. (a) masked-max with batch m2 in LDS, (b) o2-dot -> hv in LDS,
// (decoder on threads 512+ when last), (c) next-round K=128 GEMM on thr 0-255.
__global__ __launch_bounds__(1024, 8) void k12(
    const uint4* __restrict__ eg16, const int* __restrict__ jl,
    const int* __restrict__ cnt, const float* __restrict__ We,
    const float* __restrict__ m1c, const float* __restrict__ m2c,
    const float* __restrict__ o1c,
    const float* __restrict__ Wm1, const float* __restrict__ Wm2,
    const float* __restrict__ Wo1, const float* __restrict__ Wo2,
    const float* __restrict__ Wdn, const float* __restrict__ Wde,
    const float* __restrict__ zp,
    float* __restrict__ m1n, float* __restrict__ m2n, float* __restrict__ o1n,
    float* __restrict__ out, int t, int last, int do_next) {
    __shared__ float m2_lds[NN][HH];    // 64 KB
    __shared__ float agg_lds[8][HH];    // 4 KB
    __shared__ float hv_lds[8][HH];     // 4 KB
    const int tid = threadIdx.x;
    const int bid = blockIdx.x;
    const int tile = (bid & 7) * 64 + (bid >> 3);   // XCD: xcd owns 4 batches
    const int b = tile >> 4;
    const int ig = tile & 15;
    const int bi0 = b * NN + ig * 8;

    // stage batch m2 tile
    {
        const float4* src = (const float4*)(m2c + (size_t)b * NN * HH);
        float4* dst = (float4*)&m2_lds[0][0];
#pragma unroll
        for (int u = 0; u < 4; ++u) dst[u * 1024 + tid] = src[u * 1024 + tid];
    }

    const int il = tid >> 7;            // receiver 0..7 (wave-uniform)
    const int h = tid & 127;
    const int bi = bi0 + il;

    const float we0 = We[0 * HH + h], we1 = We[1 * HH + h];
    const float we2 = We[2 * HH + h], we3 = We[3 * HH + h];
    const float we4 = We[4 * HH + h], we5 = We[5 * HH + h];
    const float we6 = We[6 * HH + h], we7 = We[7 * HH + h];
    const int cp = cnt[bi];
    const float m1v = m1c[bi * HH + h];
    const float o1v = o1c[bi * HH + h];
    const uint4* __restrict__ egp = eg16 + (size_t)bi * NN;
    const int* __restrict__ jlb = jl + bi * NN;
    __syncthreads();

    // phase a: masked max over compacted senders (batch-4 unroll, <=64 VGPR)
    float M = -3e38f;
    const int nch = cp >> 2;
    for (int ch = 0; ch < nch; ++ch) {
        const int k0 = ch * 4;
        uint4 raw[4];
        int jj[4];
        float mv[4];
#pragma unroll
        for (int s = 0; s < 4; ++s) raw[s] = egp[k0 + s];
#pragma unroll
        for (int s = 0; s < 4; ++s) jj[s] = jlb[k0 + s];
#pragma unroll
        for (int s = 0; s < 4; ++s) mv[s] = m2_lds[jj[s]][h];
#pragma unroll
        for (int s = 0; s < 4; ++s) {
            uint32_t x = raw[s].x, y = raw[s].y, z = raw[s].z, w = raw[s].w;
            float e = __uint_as_float(x << 16) * we0;
            e = fmaf(__uint_as_float(x & 0xffff0000u), we1, e);
            e = fmaf(__uint_as_float(y << 16), we2, e);
            e = fmaf(__uint_as_float(y & 0xffff0000u), we3, e);
            e = fmaf(__uint_as_float(z << 16), we4, e);
            e = fmaf(__uint_as_float(z & 0xffff0000u), we5, e);
            e = fmaf(__uint_as_float(w << 16), we6, e);
            e = fmaf(__uint_as_float(w & 0xffff0000u), we7, e);
            M = fmaxf(M, e + mv[s]);
        }
    }
    float agg = (cp > 0) ? fmaxf(m1v + M, 0.f) : -1e9f;
    agg_lds[il][h] = agg;
    __syncthreads();

    // phase b: hv = relu(o1 + agg @ Wo2)
    float acc = o1v;
    const float4* a4 = (const float4*)&agg_lds[il][0];
#pragma unroll 8
    for (int kk = 0; kk < 32; ++kk) {
        float4 a = a4[kk];
        acc = fmaf(a.x, Wo2[(kk * 4 + 0) * HH + h], acc);
        acc = fmaf(a.y, Wo2[(kk * 4 + 1) * HH + h], acc);
        acc = fmaf(a.z, Wo2[(kk * 4 + 2) * HH + h], acc);
        acc = fmaf(a.w, Wo2[(kk * 4 + 3) * HH + h], acc);
    }
    hv_lds[il][h] = fmaxf(acc, 0.f);
    __syncthreads();

    // decoder (threads 512..1023, disjoint from phase c)
    if (last && tid >= 512) {
        const int dl = (tid - 512) >> 6;   // receiver 0..7
        const int hh = (tid - 512) & 63;
        float a = 0.f, e2 = 0.f;
        const float4* h4p = (const float4*)&hv_lds[dl][0];
        const float4* ag4 = (const float4*)&agg_lds[dl][0];
#pragma unroll 8
        for (int kk = 0; kk < 32; ++kk) {
            float4 hv4 = h4p[kk];
            float4 av4 = ag4[kk];
            a = fmaf(hv4.x, Wdn[(kk * 4 + 0) * DEC + hh], a);
            a = fmaf(hv4.y, Wdn[(kk * 4 + 1) * DEC + hh], a);
            a = fmaf(hv4.z, Wdn[(kk * 4 + 2) * DEC + hh], a);
            a = fmaf(hv4.w, Wdn[(kk * 4 + 3) * DEC + hh], a);
            e2 = fmaf(av4.x, Wde[(kk * 4 + 0) * DEC + hh], e2);
            e2 = fmaf(av4.y, Wde[(kk * 4 + 1) * DEC + hh], e2);
            e2 = fmaf(av4.z, Wde[(kk * 4 + 2) * DEC + hh], e2);
            e2 = fmaf(av4.w, Wde[(kk * 4 + 3) * DEC + hh], e2);
        }
        out[(((size_t)t * BB + b) * NN + ig * 8 + dl) * DEC + hh] = a + e2;
    }

    // phase c (threads 0..255): next-round m-arrays for this block's 8 rows
    if (do_next && tid < 256) {
        const int lane = tid & 127;
        const int half = tid >> 7;
        const int h4 = half * 4;
        const float* __restrict__ W1 = Wm1 + HH * HH;
        const float* __restrict__ W2 = Wm2 + HH * HH;
        const float* __restrict__ W3 = Wo1 + HH * HH;

        float acc2[4][3];
#pragma unroll
        for (int r = 0; r < 4; ++r) {
            acc2[r][0] = 0.f; acc2[r][1] = 0.f; acc2[r][2] = 0.f;
        }
#pragma unroll 4
        for (int kk = 0; kk < 32; ++kk) {
            const int k0 = kk * 4;
            float4 z0 = *(const float4*)&hv_lds[h4 + 0][k0];
            float4 z1 = *(const float4*)&hv_lds[h4 + 1][k0];
            float4 z2 = *(const float4*)&hv_lds[h4 + 2][k0];
            float4 z3 = *(const float4*)&hv_lds[h4 + 3][k0];
#define K1U(COMP, KO)                                                   \
            {                                                           \
                const float w1 = W1[(k0 + KO) * HH + lane];             \
                const float w2 = W2[(k0 + KO) * HH + lane];             \
                const float w3 = W3[(k0 + KO) * HH + lane];             \
                acc2[0][0] = fmaf(z0.COMP, w1, acc2[0][0]);             \
                acc2[1][0] = fmaf(z1.COMP, w1, acc2[1][0]);             \
                acc2[2][0] = fmaf(z2.COMP, w1, acc2[2][0]);             \
                acc2[3][0] = fmaf(z3.COMP, w1, acc2[3][0]);             \
                acc2[0][1] = fmaf(z0.COMP, w2, acc2[0][1]);             \
                acc2[1][1] = fmaf(z1.COMP, w2, acc2[1][1]);             \
                acc2[2][1] = fmaf(z2.COMP, w2, acc2[2][1]);             \
                acc2[3][1] = fmaf(z3.COMP, w2, acc2[3][1]);             \
                acc2[0][2] = fmaf(z0.COMP, w3, acc2[0][2]);             \
                acc2[1][2] = fmaf(z1.COMP, w3, acc2[1][2]);             \
                acc2[2][2] = fmaf(z2.COMP, w3, acc2[2][2]);             \
                acc2[3][2] = fmaf(z3.COMP, w3, acc2[3][2]);             \
            }
            K1U(x, 0) K1U(y, 1) K1U(z, 2) K1U(w, 3)
#undef K1U
        }
#pragma unroll
        for (int r = 0; r < 4; ++r) {
            const int row = bi0 + h4 + r;
            m1n[(size_t)row * HH + lane] =
                acc2[r][0] + zp[((size_t)0 * 4096 + row) * HH + lane];
            m2n[(size_t)row * HH + lane] =
                acc2[r][1] + zp[((size_t)1 * 4096 + row) * HH + lane];
            o1n[(size_t)row * HH + lane] =
                acc2[r][2] + zp[((size_t)2 * 4096 + row) * HH + lane];
        }
    }
}

extern "C" void kernel_launch(void* const* d_in, const int* in_sizes, int n_in,
                              void* d_out, int out_size, void* d_ws, size_t ws_size,
                              hipStream_t stream) {
    const float* node = (const float*)d_in[0];
    const float* edge = (const float*)d_in[1];
    const float* graph = (const float*)d_in[2];
    const float* hints = (const float*)d_in[3];
    const int* adj = (const int*)d_in[4];
    const float* Wn = (const float*)d_in[5];
    const float* Wh = (const float*)d_in[6];
    const float* Wee = (const float*)d_in[7];
    const float* Wg = (const float*)d_in[8];
    const float* Wm1 = (const float*)d_in[9];
    const float* Wm2 = (const float*)d_in[10];
    const float* Wme = (const float*)d_in[11];
    const float* Wmg = (const float*)d_in[12];
    const float* Wo1 = (const float*)d_in[13];
    const float* Wo2 = (const float*)d_in[14];
    const float* Wdn = (const float*)d_in[15];
    const float* Wde = (const float*)d_in[16];

    float* ws = (float*)d_ws;
    float* base_node = ws;
    float* We = ws + 524288;
    float* mg = ws + 525312;
    uint4* eg16 = (uint4*)(ws + 529408);
    int* jl = (int*)(ws + 2626560);
    int* cnt = (int*)(ws + 3150848);
    float* zpart = ws + 3154944;
    float* bufA = ws + 28320768;
    float* bufB = ws + 29893632;
    float* out = (float*)d_out;

    const size_t MS = (size_t)4096 * HH;   // one matrix slice

    prep1<<<BB * NN, HH, 0, stream>>>(node, Wn, base_node);
    prep2<<<BB + FE, HH, 0, stream>>>(graph, Wg, Wmg, Wee, Wme, mg, We);
    prep3<<<BB * NN, HH, 0, stream>>>(edge, adj, eg16, jl, cnt);
    k0_nf<<<8192, 256, 0, stream>>>(base_node, hints, Wh, Wm1, Wm2, Wo1, mg,
                                    zpart);

    for (int r = 0; r < 48; ++r) {
        const int t = r / 3;
        const int ms = r % 3;
        const int last = (ms == 2) ? 1 : 0;
        const int tn = t + last;               // zpart step for next round
        const int do_next = (r < 47) ? 1 : 0;

        const float *m1c, *m2c, *o1c;
        if (r == 0) {                          // hidden==0 -> m_cur = zpart[0]
            m1c = zpart;
            m2c = zpart + MS;
            o1c = zpart + 2 * MS;
        } else {
            float* cb = ((r - 1) & 1) ? bufB : bufA;
            m1c = cb; m2c = cb + MS; o1c = cb + 2 * MS;
        }
        float* nb = (r & 1) ? bufB : bufA;
        float* m1n = nb;
        float* m2n = nb + MS;
        float* o1n = nb + 2 * MS;
        const float* zp = zpart + (size_t)(do_next ? tn : 0) * 3 * MS;

        k12<<<512, 1024, 0, stream>>>(eg16, jl, cnt, We, m1c, m2c, o1c,
                                      Wm1, Wm2, Wo1, Wo2, Wdn, Wde, zp,
                                      m1n, m2n, o1n, out, t, last, do_next);
    }
}